// Round 9
// baseline (486.134 us; speedup 1.0000x reference)
//
#include <hip/hip_runtime.h>

// ---------------------------------------------------------------------------
// EncoderLayer: S=1024, B=4, D=1024, H=16, dh=64, DFF=4096. fp32 I/O.
// R18: attn_fused = qk_strip + batch-softmax + PV in ONE kernel.
//  - Eliminates the 268MB scores HBM round-trip (134MB write + 134MB read)
//    that existed only because softmax-over-batch split the kernels.
//  - grid 256 (16h x 16 s-strips), 4 waves, 1 block/CU, LDS 152.6KB:
//    Ks[4][64][64] | Rw[4][2][64][64] (ring) | Ssh[4][64][72] | Eb[4][32][68]
//  - Per t-tile: GL16 volley (K x4b + Rw half x4b, source-XOR swizzle,
//    R16-verified) issued BEFORE prev tile's softmax+PV -> latency hidden;
//    2 barriers/iter. Phase1 per batch is wave-local (Eb per-wave-private
//    kills the cross-batch duplicate-write race). Phase2 = pv_smx softmax
//    + PV with V direct from global (L2-resident panel).
//  - relwT moved to ws+112M (O@0 now written by the same kernel that reads
//    relwT -> old overlap would race across blocks).
// GEMMs unchanged from R17 (chunked XCD swizzle, BK=64 GL16 / BK=32 reg-pf).
//
// Workspace map (224 MB):
//  [0,16M)    O f32
//  [16M,24M) Yq bf16  [24M,32M) Yk  [32M,40M) Yv   (contiguous for SPLIT3)
//  [40M,48M)  h1 bf16  [48M,80M) ffn1 bf16
//  [80M,96M)  ffn2 f32 (first 8MB doubles as YvT bf16 until ffn2 GEMM)
//  [96M,224M) scratch:
//    pre-qk:  xb@96M(8MB) wqb@104M wkb@106M wvb@108M relwT@112M(8MB)
//    post-attn: w1b@96M(8MB) w2b@104M(8MB)
// ---------------------------------------------------------------------------

typedef unsigned short u16;
typedef unsigned int u32;
typedef __attribute__((ext_vector_type(4))) float f32x4;
typedef __attribute__((ext_vector_type(8))) short bf16x8;
typedef __attribute__((ext_vector_type(4))) u32 u32x4;

__device__ __forceinline__ float bf2f(u16 u) { return __uint_as_float(((u32)u) << 16); }
__device__ __forceinline__ u16 f2bf(float f) {
    u32 u = __float_as_uint(f);
    u += 0x7fffu + ((u >> 16) & 1u);   // RNE
    return (u16)(u >> 16);
}
template<int DT>
__device__ __forceinline__ float load1(const void* P, size_t idx) {
    return (DT == 0) ? bf2f(((const u16*)P)[idx]) : ((const float*)P)[idx];
}

// async global->LDS DMA, 16B per lane. LDS dest linear in lane order;
// swizzle lives on the GLOBAL address (rule #21).
#define GL16(gp, lp)                                                        \
    __builtin_amdgcn_global_load_lds(                                       \
        (const __attribute__((address_space(1))) void*)(gp),                \
        (__attribute__((address_space(3))) void*)(lp), 16, 0, 0)

__global__ __launch_bounds__(256) void sentinel_ws(float* out, u32 n)
{
    for (u32 i = blockIdx.x * 256 + threadIdx.x; i < n; i += gridDim.x * 256) out[i] = 31000.0f;
}

// ---------------- fp32 -> bf16 bulk convert (n mult of 4) ------------------
__global__ __launch_bounds__(256) void cvt_f32_bf16(const float* __restrict__ s,
                                                    u16* __restrict__ d, u32 n)
{
    u32 i = (blockIdx.x * 256 + threadIdx.x) * 4;
    if (i >= n) return;
    float4 v = *(const float4*)(s + i);
    uint2 pk;
    pk.x = (u32)f2bf(v.x) | ((u32)f2bf(v.y) << 16);
    pk.y = (u32)f2bf(v.z) | ((u32)f2bf(v.w) << 16);
    *(uint2*)(d + i) = pk;
}

// ------- relwT[bh][u][d] (bf16) = relw[bh][d][u] (fp32) --------------------
__global__ __launch_bounds__(256) void relw_tr(const float* __restrict__ relw,
                                               u16* __restrict__ relwT)
{
    __shared__ __align__(16) float T[64][68];
    const int tid = threadIdx.x;
    const int bh = blockIdx.y;
    const int u0 = blockIdx.x << 6;
    {
        const int d = tid >> 2, uq = (tid & 3) << 4;
        const float* rp = relw + (size_t)bh * 65536 + (size_t)d * 1024 + u0 + uq;
#pragma unroll
        for (int i = 0; i < 4; i++)
            *(float4*)&T[d][uq + i * 4] = *(const float4*)(rp + i * 4);
    }
    __syncthreads();
    {
        const int u = tid >> 2, dq = (tid & 3) << 4;
        u32 pk[8];
#pragma unroll
        for (int p = 0; p < 8; p++) {
            float a = T[dq + p * 2][u], b = T[dq + p * 2 + 1][u];
            pk[p] = (u32)f2bf(a) | ((u32)f2bf(b) << 16);
        }
        u16* op = relwT + ((size_t)(bh * 1024 + u0 + u) << 6) + dq;
        *(uint4*)op = *(uint4*)&pk[0];
        *(uint4*)(op + 8) = *(uint4*)&pk[4];
    }
}

// ------- YvT[bh][d][t] (bf16) = Yv[(b*1024+t)*1024 + h*64+d] ---------------
__global__ __launch_bounds__(256) void yv_tr(const u16* __restrict__ Yv,
                                             u16* __restrict__ YvT)
{
    __shared__ __align__(16) u16 T[64][72];
    const int tid = threadIdx.x;
    const int bh = blockIdx.y, b = bh >> 4, h = bh & 15;
    const int t0 = blockIdx.x << 6;
    {
        const int r = tid >> 2, cq = (tid & 3) << 4;
        const u16* p = Yv + ((size_t)(b * 1024 + t0 + r) << 10) + h * 64 + cq;
        *(uint4*)&T[r][cq] = *(const uint4*)p;
        *(uint4*)&T[r][cq + 8] = *(const uint4*)(p + 8);
    }
    __syncthreads();
    {
        const int d = tid >> 2, tq = (tid & 3) << 4;
        u16 vals[16];
#pragma unroll
        for (int p = 0; p < 16; p++) vals[p] = T[tq + p][d];
        u16* op = YvT + (((size_t)bh * 64 + d) << 10) + t0 + tq;
        *(uint4*)op = ((uint4*)vals)[0];
        *(uint4*)(op + 8) = ((uint4*)vals)[1];
    }
}

// --------------- MFMA GEMM: C[M,N] = act(A[M,K] @ B[N,K]^T + bias) ---------
// 128x128 tile, 4 waves, 4x4 mfma per wave. Chunked XCD swizzle (CHX,CHY).
// STAGE=1: BK=64 GL16 single-buffer; STAGE=0: BK=32 register-prefetch.
template<int RELU, int OUT_F32, int HAS_BIAS, int SPLIT3, int STAGE,
         int CHX, int CHY>
__global__ __launch_bounds__(256) void mfma_gemm(
    const u16* __restrict__ A, const u16* __restrict__ B,
    const float* __restrict__ bias, void* __restrict__ Cout,
    int M, int N, int K)
{
    __shared__ __align__(16) u16 As[8192];
    __shared__ __align__(16) u16 Bs[8192];
    const int tid = threadIdx.x;
    const int wave = tid >> 6, lane = tid & 63;
    const int quad = lane >> 4, l16 = lane & 15;

    constexpr int S = CHX * CHY;
    const int l = blockIdx.y * gridDim.x + blockIdx.x;
    const int j = l >> 3;
    const int c = (l & 7) + ((j / S) << 3);
    const int w = j % S;
    const int nxc = gridDim.x / CHX;
    const int bx = (c % nxc) * CHX + (w % CHX);
    const int by = (c / nxc) * CHY + (w / CHX);
    const int m0 = by << 7, n0 = bx << 7;
    const int wm = (wave >> 1) << 6, wn = (wave & 1) << 6;

    f32x4 acc[4][4];
#pragma unroll
    for (int i = 0; i < 4; i++)
#pragma unroll
        for (int jj = 0; jj < 4; jj++) acc[i][jj] = (f32x4){0.f, 0.f, 0.f, 0.f};

    if (STAGE) {
        const int srow = tid >> 3;
        const int csw = ((tid & 7) ^ ((tid >> 3) & 7)) << 3;
        const u16* Ags = A + (size_t)(m0 + srow) * K + csw;
        const u16* Bgs = B + (size_t)(n0 + srow) * K + csw;
        const int rx = (l16 & 7) << 3;

        for (int k0 = 0; k0 < K; k0 += 64) {
            __syncthreads();
#pragma unroll
            for (int i = 0; i < 4; i++) {
                GL16(Ags + (size_t)(i * 32) * K + k0, &As[(i * 256 + tid) * 8]);
                GL16(Bgs + (size_t)(i * 32) * K + k0, &Bs[(i * 256 + tid) * 8]);
            }
            __syncthreads();

#pragma unroll
            for (int kk = 0; kk < 2; kk++) {
                bf16x8 af[4], bfr[4];
#pragma unroll
                for (int mi = 0; mi < 4; mi++)
                    af[mi] = *(const bf16x8*)(As + ((wm + mi * 16 + l16) << 6) +
                                              ((((kk * 4 + quad) << 3) ^ rx)));
#pragma unroll
                for (int ni = 0; ni < 4; ni++)
                    bfr[ni] = *(const bf16x8*)(Bs + ((wn + ni * 16 + l16) << 6) +
                                               ((((kk * 4 + quad) << 3) ^ rx)));
#pragma unroll
                for (int mi = 0; mi < 4; mi++)
#pragma unroll
                    for (int ni = 0; ni < 4; ni++)
                        acc[mi][ni] = __builtin_amdgcn_mfma_f32_16x16x32_bf16(
                            af[mi], bfr[ni], acc[mi][ni], 0, 0, 0);
            }
        }
    } else {
        const int r0 = tid >> 2;
        const int csw = ((tid & 3) ^ ((r0 >> 1) & 3)) << 3;
        const u16* Ag0 = A + (size_t)(m0 + r0) * K + csw;
        const u16* Ag1 = A + (size_t)(m0 + r0 + 64) * K + csw;
        const u16* Bg0 = B + (size_t)(n0 + r0) * K + csw;
        const u16* Bg1 = B + (size_t)(n0 + r0 + 64) * K + csw;
        const int pb = ((quad ^ ((l16 >> 1) & 3)) << 3);

        uint4 a0 = *(const uint4*)(Ag0);
        uint4 a1 = *(const uint4*)(Ag1);
        uint4 b0 = *(const uint4*)(Bg0);
        uint4 b1 = *(const uint4*)(Bg1);

        for (int k0 = 0; k0 < K; k0 += 32) {
            __syncthreads();
            *(uint4*)(As + tid * 8)        = a0;
            *(uint4*)(As + 2048 + tid * 8) = a1;
            *(uint4*)(Bs + tid * 8)        = b0;
            *(uint4*)(Bs + 2048 + tid * 8) = b1;
            __syncthreads();

            if (k0 + 32 < K) {
                a0 = *(const uint4*)(Ag0 + k0 + 32);
                a1 = *(const uint4*)(Ag1 + k0 + 32);
                b0 = *(const uint4*)(Bg0 + k0 + 32);
                b1 = *(const uint4*)(Bg1 + k0 + 32);
            }

            bf16x8 af[4], bfr[4];
#pragma unroll
            for (int mi = 0; mi < 4; mi++)
                af[mi] = *(const bf16x8*)(As + ((wm + mi * 16 + l16) << 5) + pb);
#pragma unroll
            for (int ni = 0; ni < 4; ni++)
                bfr[ni] = *(const bf16x8*)(Bs + ((wn + ni * 16 + l16) << 5) + pb);
#pragma unroll
            for (int mi = 0; mi < 4; mi++)
#pragma unroll
                for (int ni = 0; ni < 4; ni++)
                    acc[mi][ni] = __builtin_amdgcn_mfma_f32_16x16x32_bf16(
                        af[mi], bfr[ni], acc[mi][ni], 0, 0, 0);
        }
    }

    float bb[4];
#pragma unroll
    for (int ni = 0; ni < 4; ni++)
        bb[ni] = HAS_BIAS ? bias[n0 + wn + ni * 16 + l16] : 0.f;

#pragma unroll
    for (int mi = 0; mi < 4; mi++) {
#pragma unroll
        for (int ni = 0; ni < 4; ni++) {
            const int col = n0 + wn + ni * 16 + l16;
            const size_t cb = SPLIT3
                ? (((size_t)(col >> 10) << 22) + (size_t)(col & 1023))
                : (size_t)col;
#pragma unroll
            for (int r = 0; r < 4; r++) {
                const int row = m0 + wm + mi * 16 + quad * 4 + r;
                float v = acc[mi][ni][r] + bb[ni];
                if (RELU) v = fmaxf(v, 0.f);
                const size_t idx = SPLIT3 ? (cb + ((size_t)row << 10))
                                          : ((size_t)row * N + cb);
                if (OUT_F32) ((float*)Cout)[idx] = v;
                else ((u16*)Cout)[idx] = f2bf(v);
            }
        }
    }
}

// ------------- fused attention: QK^T/8 + skew + batch-softmax + PV ---------
// grid 256 = (16h x 16 s-strips), 4 waves, 1 block/CU.
// Per t-tile: GL16 volley (K x4b, Rw half x4b) -> prev-tile softmax+PV
// (overlaps DMA) -> barrier -> per-batch QK+E+combine into Ssh[b] (wave-
// local; Eb per-wave-private) -> barrier. Epilogue: last softmax+PV, O out.
__global__ __launch_bounds__(256, 1) void attn_fused(
    const u16* __restrict__ Yq, const u16* __restrict__ Yk,
    const u16* __restrict__ relwT, const u16* __restrict__ YvT,
    float* __restrict__ O)
{
    // u16 elems: Ks 4*4096 | Rw 8*4096 | Ssh 4*4608 | Eb 4*2176  = 152576 B
    __shared__ __align__(16) u16 lds[76288];
    u16* Ks  = lds;                // [b][64][64], XOR-swizzled slots
    u16* Rw  = lds + 16384;        // [b][2][64][64] ring, XOR-swizzled
    u16* Ssh = lds + 49152;        // [b][64][72] raw combined scores
    u16* Ebp = lds + 67584;        // per-wave [32][68]

    const int tid = threadIdx.x;
    const int wave = tid >> 6, lane = tid & 63;
    const int quad = lane >> 4, l16 = lane & 15;
    const int ws = wave >> 1, wt = wave & 1;

    const int bid = blockIdx.x;
    const int swz = (bid & 7) * 32 + (bid >> 3);   // h-major XCD locality
    const int h = swz >> 4, si = swz & 15;
    const int s0 = si << 6;
    const int qb0 = 15 - si;
    const int tau0 = 2 + wt * 2 - ws * 2;
    u16* EbW = Ebp + wave * 2176;

    // Q fragments, 4 batches (persistent)
    bf16x8 qf[4][2][2];
#pragma unroll
    for (int b = 0; b < 4; b++)
#pragma unroll
        for (int mi = 0; mi < 2; mi++)
#pragma unroll
            for (int kk = 0; kk < 2; kk++)
                qf[b][mi][kk] = *(const bf16x8*)(Yq +
                    ((size_t)(b * 1024 + s0 + ws * 32 + mi * 16 + l16) << 10) +
                    h * 64 + kk * 32 + quad * 8);

    // O accumulators [b][nj]
    f32x4 acc[4][4];
#pragma unroll
    for (int b = 0; b < 4; b++)
#pragma unroll
        for (int nj = 0; nj < 4; nj++) acc[b][nj] = (f32x4){0.f, 0.f, 0.f, 0.f};

    // Phase 2: batch-softmax + PV for tile at t0p (reads Ssh, V from global)
    auto phase2 = [&](int t0p) {
#pragma unroll
        for (int kk = 0; kk < 2; kk++) {
            u32x4 pcf[4];
#pragma unroll
            for (int b = 0; b < 4; b++)
                pcf[b] = *(const u32x4*)(Ssh + b * 4608 +
                                         (wave * 16 + l16) * 72 + kk * 32 + quad * 8);
            u32x4 aw[4];
#pragma unroll
            for (int j = 0; j < 4; j++) {
                float x0[4], x1[4];
#pragma unroll
                for (int b = 0; b < 4; b++) {
                    const u32 wd = pcf[b][j];
                    x0[b] = __uint_as_float(wd << 16);
                    x1[b] = __uint_as_float(wd & 0xffff0000u);
                }
                const float m0 = fmaxf(fmaxf(x0[0], x0[1]), fmaxf(x0[2], x0[3]));
                const float m1 = fmaxf(fmaxf(x1[0], x1[1]), fmaxf(x1[2], x1[3]));
                float s0v = 0.f, s1v = 0.f;
#pragma unroll
                for (int b = 0; b < 4; b++) {
                    x0[b] = __expf(x0[b] - m0); s0v += x0[b];
                    x1[b] = __expf(x1[b] - m1); s1v += x1[b];
                }
                const float r0 = 1.f / s0v, r1 = 1.f / s1v;
#pragma unroll
                for (int b = 0; b < 4; b++)
                    aw[b][j] = (u32)f2bf(x0[b] * r0) | ((u32)f2bf(x1[b] * r1) << 16);
            }
#pragma unroll
            for (int b = 0; b < 4; b++) {
                const bf16x8 af = __builtin_bit_cast(bf16x8, aw[b]);
#pragma unroll
                for (int nj = 0; nj < 4; nj++) {
                    bf16x8 bv = *(const bf16x8*)(YvT +
                        ((size_t)(b * 16 + h) << 16) + ((size_t)(nj * 16 + l16) << 10) +
                        t0p + kk * 32 + quad * 8);
                    acc[b][nj] = __builtin_amdgcn_mfma_f32_16x16x32_bf16(
                        af, bv, acc[b][nj], 0, 0, 0);
                }
            }
        }
    };

    for (int i = 0; i < 16; i++) {
        const int t0 = i << 6;

        // ---- GL16 volley for iter i (in flight across phase2 below) ----
#pragma unroll
        for (int k = 0; k < 2; k++) {
            const int idx = k * 256 + tid;
            const int row = idx >> 3;
            const int csw = ((idx & 7) ^ (row & 7)) << 3;   // source slot-XOR
#pragma unroll
            for (int b = 0; b < 4; b++)
                GL16(Yk + ((size_t)(b * 1024 + t0 + row) << 10) + h * 64 + csw,
                     Ks + b * 4096 + idx * 8);
        }
        if (i == 0) {                        // initial ring half (always valid u)
#pragma unroll
            for (int k = 0; k < 2; k++) {
                const int idx = k * 256 + tid;
                const int row = idx >> 3;
                const int csw = ((idx & 7) ^ (row & 7)) << 3;
#pragma unroll
                for (int b = 0; b < 4; b++)
                    GL16(relwT + ((size_t)((b * 16 + h) * 1024 + 960 - s0 + row) << 6) + csw,
                         Rw + (b * 2 + (qb0 & 1)) * 4096 + idx * 8);
            }
        }
        if (i <= si) {                       // new ring half; zero-fill u>=1024
            const int sl2 = (qb0 + i + 1) & 1;
#pragma unroll
            for (int k = 0; k < 2; k++) {
                const int idx = k * 256 + tid;
                const int row = idx >> 3;
                const int csw = ((idx & 7) ^ (row & 7)) << 3;
                const int u = 1024 - s0 + t0 + row;
#pragma unroll
                for (int b = 0; b < 4; b++) {
                    u16* dst = Rw + (b * 2 + sl2) * 4096 + idx * 8;
                    if (u < 1024)
                        GL16(relwT + ((size_t)((b * 16 + h) * 1024 + u) << 6) + csw, dst);
                    else
                        *(u32x4*)dst = (u32x4){0, 0, 0, 0};
                }
            }
        }

        // ---- softmax+PV of previous tile (overlaps DMA flight) ----
        if (i) phase2(t0 - 64);
        __syncthreads();                     // drain volley; Ssh(prev) consumed

        // ---- Phase 1: per batch QK + E + combine -> Ssh[b] (wave-local) ----
        const int eact = (i <= si);
        const int qb = qb0 + i;
#pragma unroll
        for (int b = 0; b < 4; b++) {
            f32x4 aqk[2][2];
#pragma unroll
            for (int mi = 0; mi < 2; mi++)
#pragma unroll
                for (int nj = 0; nj < 2; nj++) aqk[mi][nj] = (f32x4){0.f, 0.f, 0.f, 0.f};
#pragma unroll
            for (int kk = 0; kk < 2; kk++)
#pragma unroll
                for (int nj = 0; nj < 2; nj++) {
                    const int tr = wt * 32 + nj * 16 + l16;
                    bf16x8 kb = *(const bf16x8*)(Ks + b * 4096 + tr * 64 +
                                                 (((kk * 4 + quad) ^ (tr & 7)) << 3));
#pragma unroll
                    for (int mi = 0; mi < 2; mi++)
                        aqk[mi][nj] = __builtin_amdgcn_mfma_f32_16x16x32_bf16(
                            qf[b][mi][kk], kb, aqk[mi][nj], 0, 0, 0);
                }

            if (eact) {
                f32x4 ae[4][2];
#pragma unroll
                for (int uj = 0; uj < 4; uj++)
#pragma unroll
                    for (int mi = 0; mi < 2; mi++) ae[uj][mi] = (f32x4){0.f, 0.f, 0.f, 0.f};
#pragma unroll
                for (int kk = 0; kk < 2; kk++)
#pragma unroll
                    for (int uj = 0; uj < 4; uj++) {
                        const int tau = tau0 + uj;
                        const int ur = (tau & 3) * 16 + l16;
                        const u16* hp = Rw + (b * 2 + ((qb + (tau >> 2)) & 1)) * 4096;
                        bf16x8 ra = *(const bf16x8*)(hp + ur * 64 +
                                                     (((kk * 4 + quad) ^ (ur & 7)) << 3));
#pragma unroll
                        for (int mi = 0; mi < 2; mi++)
                            ae[uj][mi] = __builtin_amdgcn_mfma_f32_16x16x32_bf16(
                                ra, qf[b][mi][kk], ae[uj][mi], 0, 0, 0);
                    }
                // per-wave private Eb: [s_local 32][u_local 68]
#pragma unroll
                for (int uj = 0; uj < 4; uj++)
#pragma unroll
                    for (int mi = 0; mi < 2; mi++) {
                        const int rloc = mi * 16 + l16;
                        const int cb = uj * 16 + quad * 4;
                        uint2 pk;
                        pk.x = (u32)f2bf(ae[uj][mi][0]) | ((u32)f2bf(ae[uj][mi][1]) << 16);
                        pk.y = (u32)f2bf(ae[uj][mi][2]) | ((u32)f2bf(ae[uj][mi][3]) << 16);
                        *(uint2*)(EbW + rloc * 68 + cb) = pk;
                    }
            }

            // combine -> Ssh[b] (gather col = 31+16nj+l16-16mi-4quad-rr, in [0,64))
#pragma unroll
            for (int mi = 0; mi < 2; mi++)
#pragma unroll
                for (int nj = 0; nj < 2; nj++)
#pragma unroll
                    for (int rr = 0; rr < 4; rr++) {
                        const int slq = mi * 16 + quad * 4 + rr;
                        const int sl = ws * 32 + slq;
                        const int tl = wt * 32 + nj * 16 + l16;
                        float e = 0.f;
                        if (eact)
                            e = bf2f(EbW[slq * 68 + 31 + nj * 16 + l16 -
                                         mi * 16 - quad * 4 - rr]);
                        Ssh[b * 4608 + sl * 72 + tl] =
                            f2bf(aqk[mi][nj][rr] * 0.125f + e);
                    }
        }
        __syncthreads();                     // Ssh visible to all waves
    }
    phase2(960);                             // last tile

    // ---- O write ----
#pragma unroll
    for (int b = 0; b < 4; b++)
#pragma unroll
        for (int nj = 0; nj < 4; nj++)
#pragma unroll
            for (int rr = 0; rr < 4; rr++) {
                const int row = s0 + wave * 16 + quad * 4 + rr;
                O[((((size_t)(b * 16 + h) << 10) + row) << 6) + nj * 16 + l16] =
                    acc[b][nj][rr];
            }
}

// ------------- out = LN(A + f32 B) * g + beta ------------------------------
template<int DTA, int OUT_F32>
__global__ __launch_bounds__(256) void add_ln(
    const void* __restrict__ A, const float* __restrict__ Bf,
    const float* __restrict__ g, const float* __restrict__ beta,
    void* __restrict__ out)
{
    const int row = blockIdx.x;
    const int tid = threadIdx.x;
    const size_t base = (size_t)row * 1024;
    float v[4], s1 = 0.f, s2 = 0.f;
#pragma unroll
    for (int k = 0; k < 4; k++) {
        const int c = k * 256 + tid;
        float t = load1<DTA>(A, base + c) + Bf[base + c];
        v[k] = t; s1 += t; s2 += t * t;
    }
#pragma unroll
    for (int m = 1; m < 64; m <<= 1) {
        s1 += __shfl_xor(s1, m, 64);
        s2 += __shfl_xor(s2, m, 64);
    }
    __shared__ float red[8];
    if ((tid & 63) == 0) { red[(tid >> 6) * 2] = s1; red[(tid >> 6) * 2 + 1] = s2; }
    __syncthreads();
    s1 = red[0] + red[2] + red[4] + red[6];
    s2 = red[1] + red[3] + red[5] + red[7];
    const float mean = s1 * (1.f / 1024.f);
    const float var = s2 * (1.f / 1024.f) - mean * mean;
    const float rstd = rsqrtf(var + 1e-5f);
#pragma unroll
    for (int k = 0; k < 4; k++) {
        const int c = k * 256 + tid;
        float o = (v[k] - mean) * rstd * g[c] + beta[c];
        if (OUT_F32) ((float*)out)[base + c] = o;
        else ((u16*)out)[base + c] = f2bf(o);
    }
}

// ---------------------------------------------------------------------------
extern "C" void kernel_launch(void* const* d_in, const int* in_sizes, int n_in,
                              void* d_out, int out_size, void* d_ws, size_t ws_size,
                              hipStream_t stream)
{
    const float* x    = (const float*)d_in[0];
    const float* wq   = (const float*)d_in[1];
    const float* wk   = (const float*)d_in[2];
    const float* wv   = (const float*)d_in[3];
    const float* relw = (const float*)d_in[4];
    const float* g1   = (const float*)d_in[5];
    const float* be1  = (const float*)d_in[6];
    const float* g2   = (const float*)d_in[7];
    const float* be2  = (const float*)d_in[8];
    const float* w1   = (const float*)d_in[9];
    const float* b1   = (const float*)d_in[10];
    const float* w2   = (const float*)d_in[11];
    const float* b2   = (const float*)d_in[12];

    const size_t NEEDED = ((size_t)224 << 20);
    if (ws_size < NEEDED) {
        sentinel_ws<<<dim3(1024), dim3(256), 0, stream>>>((float*)d_out, (u32)out_size);
        return;
    }

    char* ws = (char*)d_ws;
    float* O     = (float*)(ws);
    u16*   Yq    = (u16*)(ws + ((size_t)16 << 20));             // Yq/Yk/Yv contig
    u16*   Yk    = (u16*)(ws + ((size_t)24 << 20));
    u16*   Yv    = (u16*)(ws + ((size_t)32 << 20));
    u16*   h1    = (u16*)(ws + ((size_t)40 << 20));
    u16*   ffn1  = (u16*)(ws + ((size_t)48 << 20));
    float* ffn2  = (float*)(ws + ((size_t)80 << 20));
    u16*   YvT   = (u16*)(ws + ((size_t)80 << 20));             // dies before ffn2
    u16*   xb    = (u16*)(ws + ((size_t)96 << 20));             // pre-qk
    u16*   wqb   = (u16*)(ws + ((size_t)104 << 20));            // wq|wk|wv contig
    u16*   wkb   = (u16*)(ws + ((size_t)106 << 20));
    u16*   wvb   = (u16*)(ws + ((size_t)108 << 20));
    u16*   relwT = (u16*)(ws + ((size_t)112 << 20));            // dies after attn
    u16*   w1b   = (u16*)(ws + ((size_t)96 << 20));             // post-attn
    u16*   w2b   = (u16*)(ws + ((size_t)104 << 20));

    dim3 blk(256);
    const u32 M4 = 4u << 20, M1 = 1u << 20;

    // fp32 -> bf16 staging + relw transpose
    cvt_f32_bf16<<<dim3(M4 / 1024), blk, 0, stream>>>(x,  xb,  M4);
    cvt_f32_bf16<<<dim3(M1 / 1024), blk, 0, stream>>>(wq, wqb, M1);
    cvt_f32_bf16<<<dim3(M1 / 1024), blk, 0, stream>>>(wk, wkb, M1);
    cvt_f32_bf16<<<dim3(M1 / 1024), blk, 0, stream>>>(wv, wvb, M1);
    relw_tr<<<dim3(16, 64), blk, 0, stream>>>(relw, relwT);

    // fused QKV projection: B=[wq;wk;wv] (3072x1024), C split into Yq/Yk/Yv
    mfma_gemm<0,0,0,1,1,12,8><<<dim3(24, 32), blk, 0, stream>>>(
        xb, wqb, nullptr, Yq, 4096, 3072, 1024);
    yv_tr<<<dim3(16, 64), blk, 0, stream>>>(Yv, YvT);

    // fused attention (QK^T + skew + batch-softmax + PV), no scores in HBM
    attn_fused<<<dim3(256), blk, 0, stream>>>(Yq, Yk, relwT, YvT, O);

    // h1 = LN(x + attn_out)
    add_ln<1,0><<<dim3(4096), blk, 0, stream>>>(x, O, g1, be1, h1);

    // FFN weights -> bf16 (scratch region dead after attn)
    cvt_f32_bf16<<<dim3(M4 / 1024), blk, 0, stream>>>(w1, w1b, M4);
    cvt_f32_bf16<<<dim3(M4 / 1024), blk, 0, stream>>>(w2, w2b, M4);

    // FFN: ffn1 chunk 8x16 (STAGE=1); ffn2 chunk 4x8 (STAGE=0)
    mfma_gemm<1,0,1,0,1,8,16><<<dim3(32, 32), blk, 0, stream>>>(h1, w1b, b1, ffn1, 4096, 4096, 1024);
    mfma_gemm<0,1,1,0,0,4,8><<<dim3(8, 32), blk, 0, stream>>>(ffn1, w2b, b2, ffn2, 4096, 1024, 4096);

    // out = LN(h1 + ffn) -> f32
    add_ln<0,1><<<dim3(4096), blk, 0, stream>>>(h1, ffn2, g2, be2, (float*)d_out);
}

// Round 10
// 441.899 us; speedup vs baseline: 1.1001x; 1.1001x over previous
//
#include <hip/hip_runtime.h>

// ---------------------------------------------------------------------------
// EncoderLayer: S=1024, B=4, D=1024, H=16, dh=64, DFF=4096. fp32 I/O.
// R19: attn_fused at 512 threads / 8 waves (R18 ran 1 blk/CU x 4 waves =
// 1 wave/SIMD -> zero latency hiding; HBM 2.2%, MFMA 5.4%, occ 11%).
//  - Phase1 waves = (ws in 4) x (wt in 2): 16s x 32t quadrant each.
//    tau0 = 3+2wt-ws, 3 E-tiles (6 E-MFMA, was 16); Eb per-wave [16][52]
//    -> 8 waves = 13KB (R18's 8-wave blocker). gather col =
//    15+16nj+l16-4quad-rr in [0,46].
//  - Phase2 waves = (row-group in 4) x (nj-half in 2): 16 MFMA each.
//  - Volley: 512 lanes = 1 GL16/batch for K tile and Rw half.
//  - LDS: Ks 32K | Rw 64K | Ssh 36K | Eb 13K = 145KB; 2 waves/SIMD.
// GEMMs/LN/transposes unchanged from R18 (R17 chunked-XCD versions).
//
// Workspace map (224 MB):
//  [0,16M)    O f32
//  [16M,24M) Yq bf16  [24M,32M) Yk  [32M,40M) Yv   (contiguous for SPLIT3)
//  [40M,48M)  h1 bf16  [48M,80M) ffn1 bf16
//  [80M,96M)  ffn2 f32 (first 8MB doubles as YvT bf16 until ffn2 GEMM)
//  [96M,224M) scratch:
//    pre-qk:  xb@96M(8MB) wqb@104M wkb@106M wvb@108M relwT@112M(8MB)
//    post-attn: w1b@96M(8MB) w2b@104M(8MB)
// ---------------------------------------------------------------------------

typedef unsigned short u16;
typedef unsigned int u32;
typedef __attribute__((ext_vector_type(4))) float f32x4;
typedef __attribute__((ext_vector_type(8))) short bf16x8;
typedef __attribute__((ext_vector_type(4))) u32 u32x4;

__device__ __forceinline__ float bf2f(u16 u) { return __uint_as_float(((u32)u) << 16); }
__device__ __forceinline__ u16 f2bf(float f) {
    u32 u = __float_as_uint(f);
    u += 0x7fffu + ((u >> 16) & 1u);   // RNE
    return (u16)(u >> 16);
}
template<int DT>
__device__ __forceinline__ float load1(const void* P, size_t idx) {
    return (DT == 0) ? bf2f(((const u16*)P)[idx]) : ((const float*)P)[idx];
}

// async global->LDS DMA, 16B per lane. LDS dest linear in lane order;
// swizzle lives on the GLOBAL address (rule #21).
#define GL16(gp, lp)                                                        \
    __builtin_amdgcn_global_load_lds(                                       \
        (const __attribute__((address_space(1))) void*)(gp),                \
        (__attribute__((address_space(3))) void*)(lp), 16, 0, 0)

__global__ __launch_bounds__(256) void sentinel_ws(float* out, u32 n)
{
    for (u32 i = blockIdx.x * 256 + threadIdx.x; i < n; i += gridDim.x * 256) out[i] = 31000.0f;
}

// ---------------- fp32 -> bf16 bulk convert (n mult of 4) ------------------
__global__ __launch_bounds__(256) void cvt_f32_bf16(const float* __restrict__ s,
                                                    u16* __restrict__ d, u32 n)
{
    u32 i = (blockIdx.x * 256 + threadIdx.x) * 4;
    if (i >= n) return;
    float4 v = *(const float4*)(s + i);
    uint2 pk;
    pk.x = (u32)f2bf(v.x) | ((u32)f2bf(v.y) << 16);
    pk.y = (u32)f2bf(v.z) | ((u32)f2bf(v.w) << 16);
    *(uint2*)(d + i) = pk;
}

// ------- relwT[bh][u][d] (bf16) = relw[bh][d][u] (fp32) --------------------
__global__ __launch_bounds__(256) void relw_tr(const float* __restrict__ relw,
                                               u16* __restrict__ relwT)
{
    __shared__ __align__(16) float T[64][68];
    const int tid = threadIdx.x;
    const int bh = blockIdx.y;
    const int u0 = blockIdx.x << 6;
    {
        const int d = tid >> 2, uq = (tid & 3) << 4;
        const float* rp = relw + (size_t)bh * 65536 + (size_t)d * 1024 + u0 + uq;
#pragma unroll
        for (int i = 0; i < 4; i++)
            *(float4*)&T[d][uq + i * 4] = *(const float4*)(rp + i * 4);
    }
    __syncthreads();
    {
        const int u = tid >> 2, dq = (tid & 3) << 4;
        u32 pk[8];
#pragma unroll
        for (int p = 0; p < 8; p++) {
            float a = T[dq + p * 2][u], b = T[dq + p * 2 + 1][u];
            pk[p] = (u32)f2bf(a) | ((u32)f2bf(b) << 16);
        }
        u16* op = relwT + ((size_t)(bh * 1024 + u0 + u) << 6) + dq;
        *(uint4*)op = *(uint4*)&pk[0];
        *(uint4*)(op + 8) = *(uint4*)&pk[4];
    }
}

// ------- YvT[bh][d][t] (bf16) = Yv[(b*1024+t)*1024 + h*64+d] ---------------
__global__ __launch_bounds__(256) void yv_tr(const u16* __restrict__ Yv,
                                             u16* __restrict__ YvT)
{
    __shared__ __align__(16) u16 T[64][72];
    const int tid = threadIdx.x;
    const int bh = blockIdx.y, b = bh >> 4, h = bh & 15;
    const int t0 = blockIdx.x << 6;
    {
        const int r = tid >> 2, cq = (tid & 3) << 4;
        const u16* p = Yv + ((size_t)(b * 1024 + t0 + r) << 10) + h * 64 + cq;
        *(uint4*)&T[r][cq] = *(const uint4*)p;
        *(uint4*)&T[r][cq + 8] = *(const uint4*)(p + 8);
    }
    __syncthreads();
    {
        const int d = tid >> 2, tq = (tid & 3) << 4;
        u16 vals[16];
#pragma unroll
        for (int p = 0; p < 16; p++) vals[p] = T[tq + p][d];
        u16* op = YvT + (((size_t)bh * 64 + d) << 10) + t0 + tq;
        *(uint4*)op = ((uint4*)vals)[0];
        *(uint4*)(op + 8) = ((uint4*)vals)[1];
    }
}

// --------------- MFMA GEMM: C[M,N] = act(A[M,K] @ B[N,K]^T + bias) ---------
// 128x128 tile, 4 waves, 4x4 mfma per wave. Chunked XCD swizzle (CHX,CHY).
// STAGE=1: BK=64 GL16 single-buffer; STAGE=0: BK=32 register-prefetch.
template<int RELU, int OUT_F32, int HAS_BIAS, int SPLIT3, int STAGE,
         int CHX, int CHY>
__global__ __launch_bounds__(256) void mfma_gemm(
    const u16* __restrict__ A, const u16* __restrict__ B,
    const float* __restrict__ bias, void* __restrict__ Cout,
    int M, int N, int K)
{
    __shared__ __align__(16) u16 As[8192];
    __shared__ __align__(16) u16 Bs[8192];
    const int tid = threadIdx.x;
    const int wave = tid >> 6, lane = tid & 63;
    const int quad = lane >> 4, l16 = lane & 15;

    constexpr int S = CHX * CHY;
    const int l = blockIdx.y * gridDim.x + blockIdx.x;
    const int j = l >> 3;
    const int c = (l & 7) + ((j / S) << 3);
    const int w = j % S;
    const int nxc = gridDim.x / CHX;
    const int bx = (c % nxc) * CHX + (w % CHX);
    const int by = (c / nxc) * CHY + (w / CHX);
    const int m0 = by << 7, n0 = bx << 7;
    const int wm = (wave >> 1) << 6, wn = (wave & 1) << 6;

    f32x4 acc[4][4];
#pragma unroll
    for (int i = 0; i < 4; i++)
#pragma unroll
        for (int jj = 0; jj < 4; jj++) acc[i][jj] = (f32x4){0.f, 0.f, 0.f, 0.f};

    if (STAGE) {
        const int srow = tid >> 3;
        const int csw = ((tid & 7) ^ ((tid >> 3) & 7)) << 3;
        const u16* Ags = A + (size_t)(m0 + srow) * K + csw;
        const u16* Bgs = B + (size_t)(n0 + srow) * K + csw;
        const int rx = (l16 & 7) << 3;

        for (int k0 = 0; k0 < K; k0 += 64) {
            __syncthreads();
#pragma unroll
            for (int i = 0; i < 4; i++) {
                GL16(Ags + (size_t)(i * 32) * K + k0, &As[(i * 256 + tid) * 8]);
                GL16(Bgs + (size_t)(i * 32) * K + k0, &Bs[(i * 256 + tid) * 8]);
            }
            __syncthreads();

#pragma unroll
            for (int kk = 0; kk < 2; kk++) {
                bf16x8 af[4], bfr[4];
#pragma unroll
                for (int mi = 0; mi < 4; mi++)
                    af[mi] = *(const bf16x8*)(As + ((wm + mi * 16 + l16) << 6) +
                                              ((((kk * 4 + quad) << 3) ^ rx)));
#pragma unroll
                for (int ni = 0; ni < 4; ni++)
                    bfr[ni] = *(const bf16x8*)(Bs + ((wn + ni * 16 + l16) << 6) +
                                               ((((kk * 4 + quad) << 3) ^ rx)));
#pragma unroll
                for (int mi = 0; mi < 4; mi++)
#pragma unroll
                    for (int ni = 0; ni < 4; ni++)
                        acc[mi][ni] = __builtin_amdgcn_mfma_f32_16x16x32_bf16(
                            af[mi], bfr[ni], acc[mi][ni], 0, 0, 0);
            }
        }
    } else {
        const int r0 = tid >> 2;
        const int csw = ((tid & 3) ^ ((r0 >> 1) & 3)) << 3;
        const u16* Ag0 = A + (size_t)(m0 + r0) * K + csw;
        const u16* Ag1 = A + (size_t)(m0 + r0 + 64) * K + csw;
        const u16* Bg0 = B + (size_t)(n0 + r0) * K + csw;
        const u16* Bg1 = B + (size_t)(n0 + r0 + 64) * K + csw;
        const int pb = ((quad ^ ((l16 >> 1) & 3)) << 3);

        uint4 a0 = *(const uint4*)(Ag0);
        uint4 a1 = *(const uint4*)(Ag1);
        uint4 b0 = *(const uint4*)(Bg0);
        uint4 b1 = *(const uint4*)(Bg1);

        for (int k0 = 0; k0 < K; k0 += 32) {
            __syncthreads();
            *(uint4*)(As + tid * 8)        = a0;
            *(uint4*)(As + 2048 + tid * 8) = a1;
            *(uint4*)(Bs + tid * 8)        = b0;
            *(uint4*)(Bs + 2048 + tid * 8) = b1;
            __syncthreads();

            if (k0 + 32 < K) {
                a0 = *(const uint4*)(Ag0 + k0 + 32);
                a1 = *(const uint4*)(Ag1 + k0 + 32);
                b0 = *(const uint4*)(Bg0 + k0 + 32);
                b1 = *(const uint4*)(Bg1 + k0 + 32);
            }

            bf16x8 af[4], bfr[4];
#pragma unroll
            for (int mi = 0; mi < 4; mi++)
                af[mi] = *(const bf16x8*)(As + ((wm + mi * 16 + l16) << 5) + pb);
#pragma unroll
            for (int ni = 0; ni < 4; ni++)
                bfr[ni] = *(const bf16x8*)(Bs + ((wn + ni * 16 + l16) << 5) + pb);
#pragma unroll
            for (int mi = 0; mi < 4; mi++)
#pragma unroll
                for (int ni = 0; ni < 4; ni++)
                    acc[mi][ni] = __builtin_amdgcn_mfma_f32_16x16x32_bf16(
                        af[mi], bfr[ni], acc[mi][ni], 0, 0, 0);
        }
    }

    float bb[4];
#pragma unroll
    for (int ni = 0; ni < 4; ni++)
        bb[ni] = HAS_BIAS ? bias[n0 + wn + ni * 16 + l16] : 0.f;

#pragma unroll
    for (int mi = 0; mi < 4; mi++) {
#pragma unroll
        for (int ni = 0; ni < 4; ni++) {
            const int col = n0 + wn + ni * 16 + l16;
            const size_t cb = SPLIT3
                ? (((size_t)(col >> 10) << 22) + (size_t)(col & 1023))
                : (size_t)col;
#pragma unroll
            for (int r = 0; r < 4; r++) {
                const int row = m0 + wm + mi * 16 + quad * 4 + r;
                float v = acc[mi][ni][r] + bb[ni];
                if (RELU) v = fmaxf(v, 0.f);
                const size_t idx = SPLIT3 ? (cb + ((size_t)row << 10))
                                          : ((size_t)row * N + cb);
                if (OUT_F32) ((float*)Cout)[idx] = v;
                else ((u16*)Cout)[idx] = f2bf(v);
            }
        }
    }
}

// ------------- fused attention: QK^T/8 + skew + batch-softmax + PV ---------
// grid 256 = (16h x 16 s-strips), 512 threads / 8 waves, 1 block/CU.
// Phase1 waves = (ws in 4, wt in 2): 16s x 32t quadrant, 3 E-tiles, Eb
// per-wave [16][52]. Phase2 waves = (row-group in 4, nj-half in 2).
__global__ __launch_bounds__(512, 1) void attn_fused(
    const u16* __restrict__ Yq, const u16* __restrict__ Yk,
    const u16* __restrict__ relwT, const u16* __restrict__ YvT,
    float* __restrict__ O)
{
    // u16: Ks 16384 | Rw 32768 | Ssh 18432 | Eb 6656  = 74240 u16 = 145 KB
    __shared__ __align__(16) u16 lds[74240];
    u16* Ks  = lds;                // [b][64][64], XOR-swizzled slots
    u16* Rw  = lds + 16384;        // [b][2][64][64] ring, XOR-swizzled
    u16* Ssh = lds + 49152;        // [b][64][72] raw combined scores
    u16* Ebp = lds + 67584;        // 8 x per-wave [16][52]

    const int tid = threadIdx.x;
    const int wave = tid >> 6, lane = tid & 63;
    const int quad = lane >> 4, l16 = lane & 15;
    const int g4 = wave >> 1, g2 = wave & 1;   // phase1: (ws,wt); phase2: (wg,njh)

    const int bid = blockIdx.x;
    const int swz = (bid & 7) * 32 + (bid >> 3);   // h-major XCD locality
    const int h = swz >> 4, si = swz & 15;
    const int s0 = si << 6;
    const int qb0 = 15 - si;
    const int tau0w = 3 + 2 * g2 - g4;             // phase1 first E-tile
    u16* EbW = Ebp + wave * 832;                   // [16][52]

    // Q fragments, 4 batches (rows = wave's 16 s)
    bf16x8 qf[4][2];
#pragma unroll
    for (int b = 0; b < 4; b++)
#pragma unroll
        for (int kk = 0; kk < 2; kk++)
            qf[b][kk] = *(const bf16x8*)(Yq +
                ((size_t)(b * 1024 + s0 + g4 * 16 + l16) << 10) +
                h * 64 + kk * 32 + quad * 8);

    // O accumulators [b][nj-local]
    f32x4 acc[4][2];
#pragma unroll
    for (int b = 0; b < 4; b++)
#pragma unroll
        for (int nj = 0; nj < 2; nj++) acc[b][nj] = (f32x4){0.f, 0.f, 0.f, 0.f};

    // Phase 2: batch-softmax + PV (wave roles: wg=g4 rows, njh=g2 d-half)
    auto phase2 = [&](int t0p) {
#pragma unroll
        for (int kk = 0; kk < 2; kk++) {
            u32x4 pcf[4];
#pragma unroll
            for (int b = 0; b < 4; b++)
                pcf[b] = *(const u32x4*)(Ssh + b * 4608 +
                                         (g4 * 16 + l16) * 72 + kk * 32 + quad * 8);
            u32x4 aw[4];
#pragma unroll
            for (int j = 0; j < 4; j++) {
                float x0[4], x1[4];
#pragma unroll
                for (int b = 0; b < 4; b++) {
                    const u32 wd = pcf[b][j];
                    x0[b] = __uint_as_float(wd << 16);
                    x1[b] = __uint_as_float(wd & 0xffff0000u);
                }
                const float m0 = fmaxf(fmaxf(x0[0], x0[1]), fmaxf(x0[2], x0[3]));
                const float m1 = fmaxf(fmaxf(x1[0], x1[1]), fmaxf(x1[2], x1[3]));
                float s0v = 0.f, s1v = 0.f;
#pragma unroll
                for (int b = 0; b < 4; b++) {
                    x0[b] = __expf(x0[b] - m0); s0v += x0[b];
                    x1[b] = __expf(x1[b] - m1); s1v += x1[b];
                }
                const float r0 = 1.f / s0v, r1 = 1.f / s1v;
#pragma unroll
                for (int b = 0; b < 4; b++)
                    aw[b][j] = (u32)f2bf(x0[b] * r0) | ((u32)f2bf(x1[b] * r1) << 16);
            }
#pragma unroll
            for (int b = 0; b < 4; b++) {
                const bf16x8 af = __builtin_bit_cast(bf16x8, aw[b]);
#pragma unroll
                for (int njl = 0; njl < 2; njl++) {
                    const int nj = g2 * 2 + njl;
                    bf16x8 bv = *(const bf16x8*)(YvT +
                        ((size_t)(b * 16 + h) << 16) + ((size_t)(nj * 16 + l16) << 10) +
                        t0p + kk * 32 + quad * 8);
                    acc[b][njl] = __builtin_amdgcn_mfma_f32_16x16x32_bf16(
                        af, bv, acc[b][njl], 0, 0, 0);
                }
            }
        }
    };

    const int vrow = tid >> 3;                         // 0..63
    const int vcsw = ((tid & 7) ^ (vrow & 7)) << 3;    // source slot-XOR

    for (int i = 0; i < 16; i++) {
        const int t0 = i << 6;

        // ---- GL16 volley for iter i (in flight across phase2 below) ----
#pragma unroll
        for (int b = 0; b < 4; b++)
            GL16(Yk + ((size_t)(b * 1024 + t0 + vrow) << 10) + h * 64 + vcsw,
                 Ks + b * 4096 + tid * 8);
        if (i == 0) {                        // initial ring half (always valid u)
#pragma unroll
            for (int b = 0; b < 4; b++)
                GL16(relwT + ((size_t)((b * 16 + h) * 1024 + 960 - s0 + vrow) << 6) + vcsw,
                     Rw + (b * 2 + (qb0 & 1)) * 4096 + tid * 8);
        }
        if (i <= si) {                       // new ring half; zero-fill u>=1024
            const int sl2 = (qb0 + i + 1) & 1;
            const int u = 1024 - s0 + t0 + vrow;
#pragma unroll
            for (int b = 0; b < 4; b++) {
                u16* dst = Rw + (b * 2 + sl2) * 4096 + tid * 8;
                if (u < 1024)
                    GL16(relwT + ((size_t)((b * 16 + h) * 1024 + u) << 6) + vcsw, dst);
                else
                    *(u32x4*)dst = (u32x4){0, 0, 0, 0};
            }
        }

        // ---- softmax+PV of previous tile (overlaps DMA flight) ----
        if (i) phase2(t0 - 64);
        __syncthreads();                     // drain volley; Ssh(prev) consumed

        // ---- Phase 1: per batch QK + E + combine -> Ssh[b] (wave-local) ----
        const int eact = (i <= si);
        const int qb = qb0 + i;
#pragma unroll
        for (int b = 0; b < 4; b++) {
            f32x4 aqk[2];
#pragma unroll
            for (int nj = 0; nj < 2; nj++) aqk[nj] = (f32x4){0.f, 0.f, 0.f, 0.f};
#pragma unroll
            for (int kk = 0; kk < 2; kk++)
#pragma unroll
                for (int nj = 0; nj < 2; nj++) {
                    const int tr = g2 * 32 + nj * 16 + l16;
                    bf16x8 kb = *(const bf16x8*)(Ks + b * 4096 + tr * 64 +
                                                 (((kk * 4 + quad) ^ (tr & 7)) << 3));
                    aqk[nj] = __builtin_amdgcn_mfma_f32_16x16x32_bf16(
                        qf[b][kk], kb, aqk[nj], 0, 0, 0);
                }

            if (eact) {
                f32x4 ae[3];
#pragma unroll
                for (int uj = 0; uj < 3; uj++) ae[uj] = (f32x4){0.f, 0.f, 0.f, 0.f};
#pragma unroll
                for (int kk = 0; kk < 2; kk++)
#pragma unroll
                    for (int uj = 0; uj < 3; uj++) {
                        const int tau = tau0w + uj;
                        const int ur = (tau & 3) * 16 + l16;
                        const u16* hp = Rw + (b * 2 + ((qb + (tau >> 2)) & 1)) * 4096;
                        bf16x8 ra = *(const bf16x8*)(hp + ur * 64 +
                                                     (((kk * 4 + quad) ^ (ur & 7)) << 3));
                        ae[uj] = __builtin_amdgcn_mfma_f32_16x16x32_bf16(
                            ra, qf[b][kk], ae[uj], 0, 0, 0);
                    }
                // per-wave private Eb [s_local 16][u_rel 52]
#pragma unroll
                for (int uj = 0; uj < 3; uj++) {
                    const int cb = uj * 16 + quad * 4;
                    uint2 pk;
                    pk.x = (u32)f2bf(ae[uj][0]) | ((u32)f2bf(ae[uj][1]) << 16);
                    pk.y = (u32)f2bf(ae[uj][2]) | ((u32)f2bf(ae[uj][3]) << 16);
                    *(uint2*)(EbW + l16 * 52 + cb) = pk;
                }
            }

            // combine -> Ssh[b]; gather col = 15+16nj+l16-4quad-rr in [0,46]
#pragma unroll
            for (int nj = 0; nj < 2; nj++)
#pragma unroll
                for (int rr = 0; rr < 4; rr++) {
                    const int slq = quad * 4 + rr;
                    const int sl = g4 * 16 + slq;
                    const int tl = g2 * 32 + nj * 16 + l16;
                    float e = 0.f;
                    if (eact)
                        e = bf2f(EbW[slq * 52 + 15 + nj * 16 + l16 - quad * 4 - rr]);
                    Ssh[b * 4608 + sl * 72 + tl] = f2bf(aqk[nj][rr] * 0.125f + e);
                }
        }
        __syncthreads();                     // Ssh visible to all waves
    }
    phase2(960);                             // last tile

    // ---- O write ----
#pragma unroll
    for (int b = 0; b < 4; b++)
#pragma unroll
        for (int njl = 0; njl < 2; njl++)
#pragma unroll
            for (int rr = 0; rr < 4; rr++) {
                const int row = s0 + g4 * 16 + quad * 4 + rr;
                const int col = (g2 * 2 + njl) * 16 + l16;
                O[((((size_t)(b * 16 + h) << 10) + row) << 6) + col] =
                    acc[b][njl][rr];
            }
}

// ------------- out = LN(A + f32 B) * g + beta ------------------------------
template<int DTA, int OUT_F32>
__global__ __launch_bounds__(256) void add_ln(
    const void* __restrict__ A, const float* __restrict__ Bf,
    const float* __restrict__ g, const float* __restrict__ beta,
    void* __restrict__ out)
{
    const int row = blockIdx.x;
    const int tid = threadIdx.x;
    const size_t base = (size_t)row * 1024;
    float v[4], s1 = 0.f, s2 = 0.f;
#pragma unroll
    for (int k = 0; k < 4; k++) {
        const int c = k * 256 + tid;
        float t = load1<DTA>(A, base + c) + Bf[base + c];
        v[k] = t; s1 += t; s2 += t * t;
    }
#pragma unroll
    for (int m = 1; m < 64; m <<= 1) {
        s1 += __shfl_xor(s1, m, 64);
        s2 += __shfl_xor(s2, m, 64);
    }
    __shared__ float red[8];
    if ((tid & 63) == 0) { red[(tid >> 6) * 2] = s1; red[(tid >> 6) * 2 + 1] = s2; }
    __syncthreads();
    s1 = red[0] + red[2] + red[4] + red[6];
    s2 = red[1] + red[3] + red[5] + red[7];
    const float mean = s1 * (1.f / 1024.f);
    const float var = s2 * (1.f / 1024.f) - mean * mean;
    const float rstd = rsqrtf(var + 1e-5f);
#pragma unroll
    for (int k = 0; k < 4; k++) {
        const int c = k * 256 + tid;
        float o = (v[k] - mean) * rstd * g[c] + beta[c];
        if (OUT_F32) ((float*)out)[base + c] = o;
        else ((u16*)out)[base + c] = f2bf(o);
    }
}

// ---------------------------------------------------------------------------
extern "C" void kernel_launch(void* const* d_in, const int* in_sizes, int n_in,
                              void* d_out, int out_size, void* d_ws, size_t ws_size,
                              hipStream_t stream)
{
    const float* x    = (const float*)d_in[0];
    const float* wq   = (const float*)d_in[1];
    const float* wk   = (const float*)d_in[2];
    const float* wv   = (const float*)d_in[3];
    const float* relw = (const float*)d_in[4];
    const float* g1   = (const float*)d_in[5];
    const float* be1  = (const float*)d_in[6];
    const float* g2   = (const float*)d_in[7];
    const float* be2  = (const float*)d_in[8];
    const float* w1   = (const float*)d_in[9];
    const float* b1   = (const float*)d_in[10];
    const float* w2   = (const float*)d_in[11];
    const float* b2   = (const float*)d_in[12];

    const size_t NEEDED = ((size_t)224 << 20);
    if (ws_size < NEEDED) {
        sentinel_ws<<<dim3(1024), dim3(256), 0, stream>>>((float*)d_out, (u32)out_size);
        return;
    }

    char* ws = (char*)d_ws;
    float* O     = (float*)(ws);
    u16*   Yq    = (u16*)(ws + ((size_t)16 << 20));             // Yq/Yk/Yv contig
    u16*   Yk    = (u16*)(ws + ((size_t)24 << 20));
    u16*   Yv    = (u16*)(ws + ((size_t)32 << 20));
    u16*   h1    = (u16*)(ws + ((size_t)40 << 20));
    u16*   ffn1  = (u16*)(ws + ((size_t)48 << 20));
    float* ffn2  = (float*)(ws + ((size_t)80 << 20));
    u16*   YvT   = (u16*)(ws + ((size_t)80 << 20));             // dies before ffn2
    u16*   xb    = (u16*)(ws + ((size_t)96 << 20));             // pre-qk
    u16*   wqb   = (u16*)(ws + ((size_t)104 << 20));            // wq|wk|wv contig
    u16*   wkb   = (u16*)(ws + ((size_t)106 << 20));
    u16*   wvb   = (u16*)(ws + ((size_t)108 << 20));
    u16*   relwT = (u16*)(ws + ((size_t)112 << 20));            // dies after attn
    u16*   w1b   = (u16*)(ws + ((size_t)96 << 20));             // post-attn
    u16*   w2b   = (u16*)(ws + ((size_t)104 << 20));

    dim3 blk(256);
    const u32 M4 = 4u << 20, M1 = 1u << 20;

    // fp32 -> bf16 staging + relw transpose
    cvt_f32_bf16<<<dim3(M4 / 1024), blk, 0, stream>>>(x,  xb,  M4);
    cvt_f32_bf16<<<dim3(M1 / 1024), blk, 0, stream>>>(wq, wqb, M1);
    cvt_f32_bf16<<<dim3(M1 / 1024), blk, 0, stream>>>(wk, wkb, M1);
    cvt_f32_bf16<<<dim3(M1 / 1024), blk, 0, stream>>>(wv, wvb, M1);
    relw_tr<<<dim3(16, 64), blk, 0, stream>>>(relw, relwT);

    // fused QKV projection: B=[wq;wk;wv] (3072x1024), C split into Yq/Yk/Yv
    mfma_gemm<0,0,0,1,1,12,8><<<dim3(24, 32), blk, 0, stream>>>(
        xb, wqb, nullptr, Yq, 4096, 3072, 1024);
    yv_tr<<<dim3(16, 64), blk, 0, stream>>>(Yv, YvT);

    // fused attention (QK^T + skew + batch-softmax + PV), 512 threads
    attn_fused<<<dim3(256), dim3(512), 0, stream>>>(Yq, Yk, relwT, YvT, O);

    // h1 = LN(x + attn_out)
    add_ln<1,0><<<dim3(4096), blk, 0, stream>>>(x, O, g1, be1, h1);

    // FFN weights -> bf16 (scratch region dead after attn)
    cvt_f32_bf16<<<dim3(M4 / 1024), blk, 0, stream>>>(w1, w1b, M4);
    cvt_f32_bf16<<<dim3(M4 / 1024), blk, 0, stream>>>(w2, w2b, M4);

    // FFN: ffn1 chunk 8x16 (STAGE=1); ffn2 chunk 4x8 (STAGE=0)
    mfma_gemm<1,0,1,0,1,8,16><<<dim3(32, 32), blk, 0, stream>>>(h1, w1b, b1, ffn1, 4096, 4096, 1024);
    mfma_gemm<0,1,1,0,0,4,8><<<dim3(8, 32), blk, 0, stream>>>(ffn1, w2b, b2, ffn2, 4096, 1024, 4096);

    // out = LN(h1 + ffn) -> f32
    add_ln<0,1><<<dim3(4096), blk, 0, stream>>>(h1, ffn2, g2, be2, (float*)d_out);
}